// Round 11
// baseline (2868.956 us; speedup 1.0000x reference)
//
#include <hip/hip_runtime.h>

typedef unsigned short u16;
typedef unsigned int u32;
typedef unsigned long long u64;
typedef __attribute__((ext_vector_type(4)))  int  i32x4;
typedef __attribute__((ext_vector_type(16))) char i8x16;

#define NPTS 131072
#define DIM  256
#define KC   2048

// 3-level fixed point: v = S1*q1 + S2*q2 + S3*q3 + eps, |eps| <= S3/2 ~ 4.8e-7
// Ratio 254 => rint(r*INV) in [-127,127]: no clamp cascade (q2/q3 clamps are
// mathematically redundant when q1 is in range: |r1| <= S1/2 -> |q2| <= 127).
// Identity S1*S3 == S2*S2 lets q2q2, q1q3, q3q1 share one accumulator weight.
constexpr float S1  = 0.0625f;                 // 127*S1 = 7.94 > max|N(0,1)|
constexpr float S2  = S1 / 254.0f;
constexpr float S3  = S2 * S2 / S1;            // = S2/254
constexpr float IS1 = 16.0f;
constexpr float IS2 = 4064.0f;                 // 254/S1
constexpr float IS3 = 1.0f / S3;
constexpr float W_A = S1 * S1;
// epilogue compares 254-scaled: v = csq254 - (254*A + B) - C/254
constexpr float R2  = 1.0f / 254.0f;

__device__ inline void quant3(float v, char& q1, char& q2, char& q3) {
    float a = fminf(fmaxf(rintf(v * IS1), -127.f), 127.f);
    float r1 = fmaf(-a, S1, v);                // exact (pow2 scale)
    float b = rintf(r1 * IS2);                 // |r1|<=S1/2 -> |b|<=127, no clamp
    float r2 = fmaf(-b, S2, r1);               // ~1-ulp error, absorbed by q3
    float c = rintf(r2 * IS3);                 // |r2|<=S2/2 -> |c|<=127
    q1 = (char)a; q2 = (char)b; q3 = (char)c;
}

// global -> LDS direct DMA; size is a literal (16 or 4 bytes per lane)
#define GLD16(gsrc, ldst) \
    __builtin_amdgcn_global_load_lds( \
        (const __attribute__((address_space(1))) void*)(gsrc), \
        (__attribute__((address_space(3))) void*)(ldst), 16, 0, 0)
#define GLD4(gsrc, ldst) \
    __builtin_amdgcn_global_load_lds( \
        (const __attribute__((address_space(1))) void*)(gsrc), \
        (__attribute__((address_space(3))) void*)(ldst), 4, 0, 0)

// ---------------------------------------------------------------------------
// Centroid prep: 16x16x64 i8 MFMA A-fragments in TILE-MAJOR order + int
// 254-scaled 0.5||c||^2. Tile g (32 centroids) = 24KB contiguous:
//   byte = g*24576 + lv*8192 + gg*4096 + kc*1024 + (kq*16 + c)*16 + j
// where for centroid n: g = n>>5, gg = (n>>4)&1, c = n&15; dim d: kc = d>>6,
// kq = (d>>4)&3, j = d&15. (Same within-level fragment map as R8, verified;
// tile-major lets assign stage one tile with 3 lane-uniform DMA calls at
// 1024 threads.) Also zeroes hist (blocks 0..7) and sums.
// ---------------------------------------------------------------------------
__global__ void cprep_kernel(const float* __restrict__ cen,
                             char* __restrict__ c_q,
                             int* __restrict__ c_sqi,
                             int* __restrict__ hist,
                             float* __restrict__ sums) {
    if (blockIdx.x < 8) hist[blockIdx.x * 256 + threadIdx.x] = 0;
    ((float4*)sums)[blockIdx.x * 256 + threadIdx.x] = (float4){0.f, 0.f, 0.f, 0.f};
    const int lane = threadIdx.x & 63;
    const int wv   = threadIdx.x >> 6;
    const int n    = blockIdx.x * 4 + wv;               // centroid row
    float4 v = ((const float4*)(cen + (size_t)n * DIM))[lane];  // dims lane*4..+3
    float ss = v.x * v.x + v.y * v.y + v.z * v.z + v.w * v.w;
    float fv[4] = {v.x, v.y, v.z, v.w};
    char q1[4], q2[4], q3[4];
#pragma unroll
    for (int j = 0; j < 4; ++j) quant3(fv[j], q1[j], q2[j], q3[j]);
    const int g  = n >> 5, gg = (n >> 4) & 1, c = n & 15;
    const int kc = lane >> 4;
    const int kq = (lane >> 2) & 3;
    const size_t base = (size_t)g * 24576 + gg * 4096 + kc * 1024
                        + (kq * 16 + c) * 16 + (lane & 3) * 4;
    u32 p1 = (u32)(unsigned char)q1[0] | ((u32)(unsigned char)q1[1] << 8) |
             ((u32)(unsigned char)q1[2] << 16) | ((u32)(unsigned char)q1[3] << 24);
    u32 p2 = (u32)(unsigned char)q2[0] | ((u32)(unsigned char)q2[1] << 8) |
             ((u32)(unsigned char)q2[2] << 16) | ((u32)(unsigned char)q2[3] << 24);
    u32 p3 = (u32)(unsigned char)q3[0] | ((u32)(unsigned char)q3[1] << 8) |
             ((u32)(unsigned char)q3[2] << 16) | ((u32)(unsigned char)q3[3] << 24);
    *(u32*)(c_q + base) = p1;
    *(u32*)(c_q + base + 8192) = p2;
    *(u32*)(c_q + base + 16384) = p3;
#pragma unroll
    for (int off = 32; off > 0; off >>= 1) ss += __shfl_xor(ss, off);
    // 254-scaled int: 0.5*ss/W_A*254 = ss*32512; |.| <= ~1.5e7 (int-exact)
    if (lane == 0) c_sqi[n] = (int)rintf(ss * (0.5f * 254.0f / W_A));
}

// ---------------------------------------------------------------------------
// Assignment via mfma_i32_16x16x64_i8, 1024-THREAD blocks (16 waves, 256 pts).
// R8 (512 thr, 16 waves/CU, VGPR 64) was LDS-pipe-bound with wave slack:
// per CU per tile, LDS demand 4608cy vs MFMA 3917cy vs wall 6414cy, while
// VGPR=64 permits 32 waves/CU (quantum 64 -> 2048/64). Same 80KB LDS now
// hosts 16 waves/block -> 2 resident blocks = 32 waves/CU, grid 512 = exactly
// 2 blocks/CU (no partial tail). Loop body, lane maps, ring discipline are
// byte-identical to R8. Staging (tile-major c_q): stage(s) = 3 uniform calls
// {16KB @size16, 4KB @size4, 4KB @size4} into buf s%3; counted vmcnt(3)
// (prologue 8 outstanding: csq(2)+s0(3)+s1(3); t=0 drains csq+s0 exactly);
// stage(t+2) issued after the barrier into the buffer read at t-1 (sealed).
// Per cen-group g: accA += q1c*q1x; accB += q1c*q2x + q2c*q1x;
// accC += q2c*q2x + q1c*q3x + q3c*q1x.
// Epilogue: v = csq254 - (254*A + B) - C/254   (mul24 exact, |A| < 2^23)
// D layout: col = lane&15 (point), row = (lane>>4)*4 + reg (m89/m121).
// ---------------------------------------------------------------------------
__global__ __launch_bounds__(1024, 8) void assign_kernel(
    const float* __restrict__ x, const char* __restrict__ c_q,
    const int* __restrict__ c_sqi, int* __restrict__ assigns,
    int* __restrict__ hist) {
    __shared__ char lds_c[3 * 24576 + 8192];   // 3 stage bufs + csq = 80KB

    const int tid  = threadIdx.x;       // 0..1023
    const int lane = tid & 63;
    const int wv   = tid >> 6;          // 0..15
    const int p16  = lane & 15;         // point within wave's 16
    const int kq   = lane >> 4;         // K-quarter / D-row group

    // ---- prologue DMA (latency hidden under quantization VALU) ----
    GLD4((const char*)c_sqi + tid * 4,        lds_c + 73728 + tid * 4);  // 4KB
    GLD4((const char*)c_sqi + 4096 + tid * 4, lds_c + 73728 + 4096 + tid * 4);
#pragma unroll
    for (int st = 0; st < 2; ++st) {           // stage 0 -> buf0, 1 -> buf1
        const char* src = c_q + (size_t)st * 24576;
        char* d = lds_c + st * 24576;
        GLD16(src + tid * 16,         d + tid * 16);           // 16KB
        GLD4 (src + 16384 + tid * 4,  d + 16384 + tid * 4);    // 4KB
        GLD4 (src + 20480 + tid * 4,  d + 20480 + tid * 4);    // 4KB
    }

    // ---- quantize: lane holds point m, dims kc*64 + kq*16 + (0..15) ----
    const int m = blockIdx.x * 256 + wv * 16 + p16;
    const float4* xr = (const float4*)(x + (size_t)m * DIM);
    i8x16 xq1[4], xq2[4], xq3[4];
#pragma unroll
    for (int kc = 0; kc < 4; ++kc) {
        float tmp[16];
#pragma unroll
        for (int j4 = 0; j4 < 4; ++j4) {
            float4 f = xr[kc * 16 + kq * 4 + j4];
            tmp[j4 * 4 + 0] = f.x; tmp[j4 * 4 + 1] = f.y;
            tmp[j4 * 4 + 2] = f.z; tmp[j4 * 4 + 3] = f.w;
        }
        i8x16 v1, v2, v3;
#pragma unroll
        for (int j = 0; j < 16; ++j) {
            char a, b, c;
            quant3(tmp[j], a, b, c);
            v1[j] = a; v2[j] = b; v3[j] = c;
        }
        xq1[kc] = v1; xq2[kc] = v2; xq3[kc] = v3;
    }

    float best = 3.4e38f;
    int bidx = 0;
    int b3 = 0;        // current stage buffer (cycles 0,1,2)
    const int* csqL = (const int*)(lds_c + 73728);

    for (int t = 0; t < 64; ++t) {
        // steady state: {stage(t), stage(t+1)} outstanding (6 loads); wait
        // own stage(t) (leave 3). t=0 also drains csq. Last tile: drain all.
        if (t == 63) {
            asm volatile("s_waitcnt vmcnt(0)" ::: "memory");
        } else {
            asm volatile("s_waitcnt vmcnt(3)" ::: "memory");
        }
        __builtin_amdgcn_s_barrier();
        __builtin_amdgcn_sched_barrier(0);
        // issue stage(t+2) into buf (b3+2)%3: fully read at tile t-1 and
        // sealed by the barrier just crossed (all waves past it).
        if (t + 2 < 64) {
            int pn = b3 + 2; if (pn >= 3) pn -= 3;
            char* d = lds_c + pn * 24576;
            const char* src = c_q + (size_t)(t + 2) * 24576;
            GLD16(src + tid * 16,        d + tid * 16);
            GLD4 (src + 16384 + tid * 4, d + 16384 + tid * 4);
            GLD4 (src + 20480 + tid * 4, d + 20480 + tid * 4);
        }
        const char* cb = lds_c + b3 * 24576;
        i32x4 accA0 = {}, accB0 = {}, accC0 = {};
        i32x4 accA1 = {}, accB1 = {}, accC1 = {};
        __builtin_amdgcn_s_setprio(1);
#pragma unroll
        for (int kc = 0; kc < 4; ++kc) {
            const int off = kc * 1024 + lane * 16;
            i32x4 c1a = __builtin_bit_cast(i32x4, *(const i8x16*)(cb + off));
            i32x4 c2a = __builtin_bit_cast(i32x4, *(const i8x16*)(cb + 8192 + off));
            i32x4 c3a = __builtin_bit_cast(i32x4, *(const i8x16*)(cb + 16384 + off));
            i32x4 c1b = __builtin_bit_cast(i32x4, *(const i8x16*)(cb + 4096 + off));
            i32x4 c2b = __builtin_bit_cast(i32x4, *(const i8x16*)(cb + 12288 + off));
            i32x4 c3b = __builtin_bit_cast(i32x4, *(const i8x16*)(cb + 20480 + off));
            i32x4 x1 = __builtin_bit_cast(i32x4, xq1[kc]);
            i32x4 x2 = __builtin_bit_cast(i32x4, xq2[kc]);
            i32x4 x3 = __builtin_bit_cast(i32x4, xq3[kc]);
            // 6 independent acc chains, g0/g1 interleaved for dep spacing
            accA0 = __builtin_amdgcn_mfma_i32_16x16x64_i8(c1a, x1, accA0, 0, 0, 0);
            accA1 = __builtin_amdgcn_mfma_i32_16x16x64_i8(c1b, x1, accA1, 0, 0, 0);
            accB0 = __builtin_amdgcn_mfma_i32_16x16x64_i8(c1a, x2, accB0, 0, 0, 0);
            accB1 = __builtin_amdgcn_mfma_i32_16x16x64_i8(c1b, x2, accB1, 0, 0, 0);
            accC0 = __builtin_amdgcn_mfma_i32_16x16x64_i8(c2a, x2, accC0, 0, 0, 0);
            accC1 = __builtin_amdgcn_mfma_i32_16x16x64_i8(c2b, x2, accC1, 0, 0, 0);
            accB0 = __builtin_amdgcn_mfma_i32_16x16x64_i8(c2a, x1, accB0, 0, 0, 0);
            accB1 = __builtin_amdgcn_mfma_i32_16x16x64_i8(c2b, x1, accB1, 0, 0, 0);
            accC0 = __builtin_amdgcn_mfma_i32_16x16x64_i8(c1a, x3, accC0, 0, 0, 0);
            accC1 = __builtin_amdgcn_mfma_i32_16x16x64_i8(c1b, x3, accC1, 0, 0, 0);
            accC0 = __builtin_amdgcn_mfma_i32_16x16x64_i8(c3a, x1, accC0, 0, 0, 0);
            accC1 = __builtin_amdgcn_mfma_i32_16x16x64_i8(c3b, x1, accC1, 0, 0, 0);
        }
        __builtin_amdgcn_s_setprio(0);
        b3 += 1; if (b3 == 3) b3 = 0;

        // epilogue: v = csq254 - (254*A + B) - C/254 (254x score, same argmin)
        // D: col = p16, row = kq*4 + r ; n = t*32 + g*16 + kq*4 + r
        {
            int4 cs0 = *(const int4*)(csqL + t * 32 + kq * 4);
            int4 cs1 = *(const int4*)(csqL + t * 32 + 16 + kq * 4);
            const int n0 = t * 32 + kq * 4;
            int csa0[4] = {cs0.x, cs0.y, cs0.z, cs0.w};
            int csa1[4] = {cs1.x, cs1.y, cs1.z, cs1.w};
#pragma unroll
            for (int r = 0; r < 4; ++r) {
                int D0 = __mul24(accA0[r], 254) + accB0[r];  // exact, |A|<2^23
                float v0 = fmaf((float)accC0[r], -R2, (float)(csa0[r] - D0));
                if (v0 < best) { best = v0; bidx = n0 + r; }
            }
#pragma unroll
            for (int r = 0; r < 4; ++r) {
                int D1 = __mul24(accA1[r], 254) + accB1[r];
                float v1 = fmaf((float)accC1[r], -R2, (float)(csa1[r] - D1));
                if (v1 < best) { best = v1; bidx = n0 + 16 + r; }
            }
        }
    }

    // merge the 4 lanes holding rows for the same point (l, l^16, l^32, l^48)
    {
        float oval = __shfl_xor(best, 16);
        int   oidx = __shfl_xor(bidx, 16);
        if (oval < best || (oval == best && oidx < bidx)) { best = oval; bidx = oidx; }
        oval = __shfl_xor(best, 32);
        oidx = __shfl_xor(bidx, 32);
        if (oval < best || (oval == best && oidx < bidx)) { best = oval; bidx = oidx; }
    }
    if (lane < 16) {
        assigns[m] = bidx;                 // m = blockIdx*256 + wv*16 + lane
        atomicAdd(&hist[bidx], 1);         // 256 atomics/block
    }
}

// Exclusive prefix sum over KC=2048 counts; one block of 256 threads x 8 each.
__global__ void scan_kernel(const int* __restrict__ hist,
                            int* __restrict__ base_,
                            int* __restrict__ cursor) {
    __shared__ int tmp[256];
    const int tid = threadIdx.x;
    int v[8], s = 0;
#pragma unroll
    for (int j = 0; j < 8; ++j) { v[j] = hist[tid * 8 + j]; s += v[j]; }
    tmp[tid] = s;
    __syncthreads();
    for (int off = 1; off < 256; off <<= 1) {
        int t = (tid >= off) ? tmp[tid - off] : 0;
        __syncthreads();
        tmp[tid] += t;
        __syncthreads();
    }
    int ex = tmp[tid] - s;
#pragma unroll
    for (int j = 0; j < 8; ++j) {
        base_[tid * 8 + j] = ex;
        cursor[tid * 8 + j] = ex;
        ex += v[j];
    }
}

__global__ void reorder_kernel(const int* __restrict__ assigns,
                               int* __restrict__ cursor,
                               int* __restrict__ order) {
    const int p = blockIdx.x * 256 + threadIdx.x;
    const int a = assigns[p];
    int pos = atomicAdd(&cursor[a], 1);
    order[pos] = p;
}

// ---------------------------------------------------------------------------
// Skew-immune segmented reduce: each block owns 256 consecutive rows of the
// SORTED order array; thread t owns dim t (coalesced 1KB row reads). Flush to
// sums[] with atomics only at cluster boundaries (block-uniform branches).
// ---------------------------------------------------------------------------
__global__ void reduce_kernel(const float* __restrict__ x,
                              const int* __restrict__ order,
                              const int* __restrict__ assigns,
                              float* __restrict__ sums) {
    const int tid = threadIdx.x;
    const int r0 = blockIdx.x * 256;
    float acc = 0.f;
    int cur = assigns[order[r0]];
    for (int r = 0; r < 256; r += 4) {
        int p0 = order[r0 + r + 0], p1 = order[r0 + r + 1];
        int p2 = order[r0 + r + 2], p3 = order[r0 + r + 3];
        float v0 = x[(size_t)p0 * DIM + tid];
        float v1 = x[(size_t)p1 * DIM + tid];
        float v2 = x[(size_t)p2 * DIM + tid];
        float v3 = x[(size_t)p3 * DIM + tid];
        int a0 = assigns[p0], a1 = assigns[p1], a2 = assigns[p2], a3 = assigns[p3];
        if (a0 != cur) { unsafeAtomicAdd(&sums[(size_t)cur * DIM + tid], acc); acc = 0.f; cur = a0; }
        acc += v0;
        if (a1 != cur) { unsafeAtomicAdd(&sums[(size_t)cur * DIM + tid], acc); acc = 0.f; cur = a1; }
        acc += v1;
        if (a2 != cur) { unsafeAtomicAdd(&sums[(size_t)cur * DIM + tid], acc); acc = 0.f; cur = a2; }
        acc += v2;
        if (a3 != cur) { unsafeAtomicAdd(&sums[(size_t)cur * DIM + tid], acc); acc = 0.f; cur = a3; }
        acc += v3;
    }
    unsafeAtomicAdd(&sums[(size_t)cur * DIM + tid], acc);
}

__global__ void finalize_kernel(const float* __restrict__ sums,
                                const int* __restrict__ hist,
                                const float* __restrict__ cen,
                                float* __restrict__ out) {
    const int id = blockIdx.x * 256 + threadIdx.x;   // KC*64 items
    const int k = id >> 6;
    const int cnt = hist[k];
    float4 s = ((const float4*)sums)[id];
    float4 c = ((const float4*)cen)[id];
    float4 o;
    if (cnt > 0) {
        float r = 1.0f / (float)cnt;
        o.x = s.x * r; o.y = s.y * r; o.z = s.z * r; o.w = s.w * r;
    } else {
        o = c;
    }
    ((float4*)out)[id] = o;
}

extern "C" void kernel_launch(void* const* d_in, const int* in_sizes, int n_in,
                              void* d_out, int out_size, void* d_ws, size_t ws_size,
                              hipStream_t stream) {
    (void)in_sizes; (void)n_in; (void)out_size; (void)ws_size;
    const float* x   = (const float*)d_in[0];
    const float* cen = (const float*)d_in[1];
    float* out = (float*)d_out;

    char* ws = (char*)d_ws;
    size_t off = 0;
    char* c_q = (char*)(ws + off);           off += (size_t)3 * KC * DIM;      // 1.5MB
    int* c_sqi = (int*)(ws + off);           off += (size_t)KC * 4;            // 8KB
    int* assigns = (int*)(ws + off);         off += (size_t)NPTS * 4;          // 512KB
    int* hist = (int*)(ws + off);            off += (size_t)KC * 4;            // 8KB
    int* base_ = (int*)(ws + off);           off += (size_t)KC * 4;            // 8KB
    int* cursor = (int*)(ws + off);          off += (size_t)KC * 4;            // 8KB
    int* order = (int*)(ws + off);           off += (size_t)NPTS * 4;          // 512KB
    float* sums = (float*)(ws + off);        off += (size_t)KC * DIM * 4;      // 2MB

    cprep_kernel<<<KC / 4, 256, 0, stream>>>(cen, c_q, c_sqi, hist, sums);
    assign_kernel<<<NPTS / 256, 1024, 0, stream>>>(x, c_q, c_sqi, assigns, hist);
    scan_kernel<<<1, 256, 0, stream>>>(hist, base_, cursor);
    reorder_kernel<<<NPTS / 256, 256, 0, stream>>>(assigns, cursor, order);
    reduce_kernel<<<NPTS / 256, 256, 0, stream>>>(x, order, assigns, sums);
    finalize_kernel<<<KC * 64 / 256, 256, 0, stream>>>(sums, hist, cen, out);
}

// Round 12
// 603.417 us; speedup vs baseline: 4.7545x; 4.7545x over previous
//
#include <hip/hip_runtime.h>

typedef unsigned short u16;
typedef unsigned int u32;
typedef unsigned long long u64;
typedef __attribute__((ext_vector_type(4)))  int  i32x4;
typedef __attribute__((ext_vector_type(16))) char i8x16;

#define NPTS 131072
#define DIM  256
#define KC   2048

// 3-level fixed point: v = S1*q1 + S2*q2 + S3*q3 + eps, |eps| <= S3/2 ~ 4.8e-7
// Ratio 254 => rint(r*INV) in [-127,127]: no clamp cascade (q2/q3 clamps are
// mathematically redundant when q1 is in range: |r1| <= S1/2 -> |q2| <= 127).
// Identity S1*S3 == S2*S2 lets q2q2, q1q3, q3q1 share one accumulator weight.
constexpr float S1  = 0.0625f;                 // 127*S1 = 7.94 > max|N(0,1)|
constexpr float S2  = S1 / 254.0f;
constexpr float S3  = S2 * S2 / S1;            // = S2/254
constexpr float IS1 = 16.0f;
constexpr float IS2 = 4064.0f;                 // 254/S1
constexpr float IS3 = 1.0f / S3;
constexpr float W_A = S1 * S1;
// epilogue compares 254-scaled: v = csq254 - (254*A + B) - C/254
constexpr float R2  = 1.0f / 254.0f;

__device__ inline void quant3(float v, char& q1, char& q2, char& q3) {
    float a = fminf(fmaxf(rintf(v * IS1), -127.f), 127.f);
    float r1 = fmaf(-a, S1, v);                // exact (pow2 scale)
    float b = rintf(r1 * IS2);                 // |r1|<=S1/2 -> |b|<=127, no clamp
    float r2 = fmaf(-b, S2, r1);               // ~1-ulp error, absorbed by q3
    float c = rintf(r2 * IS3);                 // |r2|<=S2/2 -> |c|<=127
    q1 = (char)a; q2 = (char)b; q3 = (char)c;
}

// global -> LDS direct DMA; size is a literal (16 or 4 bytes per lane)
#define GLD16(gsrc, ldst) \
    __builtin_amdgcn_global_load_lds( \
        (const __attribute__((address_space(1))) void*)(gsrc), \
        (__attribute__((address_space(3))) void*)(ldst), 16, 0, 0)
#define GLD4(gsrc, ldst) \
    __builtin_amdgcn_global_load_lds( \
        (const __attribute__((address_space(1))) void*)(gsrc), \
        (__attribute__((address_space(3))) void*)(ldst), 4, 0, 0)

// ---------------------------------------------------------------------------
// Centroid prep: 16x16x64 i8 MFMA A-fragments in TILE-MAJOR order + int
// 254-scaled 0.5||c||^2. Tile g (32 centroids) = 24KB contiguous:
//   byte = g*24576 + lv*8192 + gg*4096 + kc*1024 + (kq*16 + c)*16 + j
// where for centroid n: g = n>>5, gg = (n>>4)&1, c = n&15; dim d: kc = d>>6,
// kq = (d>>4)&3, j = d&15. (Same within-level fragment map as R8, verified;
// tile-major lets assign stage one tile with 3 lane-uniform DMA calls at
// 1024 threads.) Also zeroes hist (blocks 0..7) and sums.
// ---------------------------------------------------------------------------
__global__ void cprep_kernel(const float* __restrict__ cen,
                             char* __restrict__ c_q,
                             int* __restrict__ c_sqi,
                             int* __restrict__ hist,
                             float* __restrict__ sums) {
    if (blockIdx.x < 8) hist[blockIdx.x * 256 + threadIdx.x] = 0;
    ((float4*)sums)[blockIdx.x * 256 + threadIdx.x] = (float4){0.f, 0.f, 0.f, 0.f};
    const int lane = threadIdx.x & 63;
    const int wv   = threadIdx.x >> 6;
    const int n    = blockIdx.x * 4 + wv;               // centroid row
    float4 v = ((const float4*)(cen + (size_t)n * DIM))[lane];  // dims lane*4..+3
    float ss = v.x * v.x + v.y * v.y + v.z * v.z + v.w * v.w;
    float fv[4] = {v.x, v.y, v.z, v.w};
    char q1[4], q2[4], q3[4];
#pragma unroll
    for (int j = 0; j < 4; ++j) quant3(fv[j], q1[j], q2[j], q3[j]);
    const int g  = n >> 5, gg = (n >> 4) & 1, c = n & 15;
    const int kc = lane >> 4;
    const int kq = (lane >> 2) & 3;
    const size_t base = (size_t)g * 24576 + gg * 4096 + kc * 1024
                        + (kq * 16 + c) * 16 + (lane & 3) * 4;
    u32 p1 = (u32)(unsigned char)q1[0] | ((u32)(unsigned char)q1[1] << 8) |
             ((u32)(unsigned char)q1[2] << 16) | ((u32)(unsigned char)q1[3] << 24);
    u32 p2 = (u32)(unsigned char)q2[0] | ((u32)(unsigned char)q2[1] << 8) |
             ((u32)(unsigned char)q2[2] << 16) | ((u32)(unsigned char)q2[3] << 24);
    u32 p3 = (u32)(unsigned char)q3[0] | ((u32)(unsigned char)q3[1] << 8) |
             ((u32)(unsigned char)q3[2] << 16) | ((u32)(unsigned char)q3[3] << 24);
    *(u32*)(c_q + base) = p1;
    *(u32*)(c_q + base + 8192) = p2;
    *(u32*)(c_q + base + 16384) = p3;
#pragma unroll
    for (int off = 32; off > 0; off >>= 1) ss += __shfl_xor(ss, off);
    // 254-scaled int: 0.5*ss/W_A*254 = ss*32512; |.| <= ~1.5e7 (int-exact)
    if (lane == 0) c_sqi[n] = (int)rintf(ss * (0.5f * 254.0f / W_A));
}

// ---------------------------------------------------------------------------
// Assignment via mfma_i32_16x16x64_i8, 1024-THREAD blocks (16 waves, 256 pts).
// R8's residency cap at 16 waves/CU was LDS (8-wave blocks x 80KB -> 2
// blocks); VGPR=64 permits 32 waves/CU. 16-wave blocks lift the LDS cap
// (2 blocks x 16 waves = 32 waves at the same 160KB).
// launch_bounds(1024,4): unified reg cap 128/wave — IDENTICAL to R8's
// (512,4) cap under which this exact loop body compiled to VGPR 64, no
// spill. (R11's (1024,8) halved the cap to 64 unified -> 32 arch VGPR ->
// xq spilled -> 11GB scratch traffic. One-number fix.)
// Loop body, lane maps, ring discipline byte-identical to R8. Staging
// (tile-major c_q): stage(s) = 3 uniform calls {16KB @size16, 4KB @size4,
// 4KB @size4} into buf s%3; counted vmcnt(3) (prologue 8 outstanding:
// csq(2)+s0(3)+s1(3); t=0 drains csq+s0 exactly); stage(t+2) issued after
// the barrier into the buffer read at t-1 (sealed).
// Per cen-group g: accA += q1c*q1x; accB += q1c*q2x + q2c*q1x;
// accC += q2c*q2x + q1c*q3x + q3c*q1x.
// Epilogue: v = csq254 - (254*A + B) - C/254   (mul24 exact, |A| < 2^23)
// D layout: col = lane&15 (point), row = (lane>>4)*4 + reg (m89/m121).
// ---------------------------------------------------------------------------
__global__ __launch_bounds__(1024, 4) void assign_kernel(
    const float* __restrict__ x, const char* __restrict__ c_q,
    const int* __restrict__ c_sqi, int* __restrict__ assigns,
    int* __restrict__ hist) {
    __shared__ char lds_c[3 * 24576 + 8192];   // 3 stage bufs + csq = 80KB

    const int tid  = threadIdx.x;       // 0..1023
    const int lane = tid & 63;
    const int wv   = tid >> 6;          // 0..15
    const int p16  = lane & 15;         // point within wave's 16
    const int kq   = lane >> 4;         // K-quarter / D-row group

    // ---- prologue DMA (latency hidden under quantization VALU) ----
    GLD4((const char*)c_sqi + tid * 4,        lds_c + 73728 + tid * 4);  // 4KB
    GLD4((const char*)c_sqi + 4096 + tid * 4, lds_c + 73728 + 4096 + tid * 4);
#pragma unroll
    for (int st = 0; st < 2; ++st) {           // stage 0 -> buf0, 1 -> buf1
        const char* src = c_q + (size_t)st * 24576;
        char* d = lds_c + st * 24576;
        GLD16(src + tid * 16,         d + tid * 16);           // 16KB
        GLD4 (src + 16384 + tid * 4,  d + 16384 + tid * 4);    // 4KB
        GLD4 (src + 20480 + tid * 4,  d + 20480 + tid * 4);    // 4KB
    }

    // ---- quantize: lane holds point m, dims kc*64 + kq*16 + (0..15) ----
    const int m = blockIdx.x * 256 + wv * 16 + p16;
    const float4* xr = (const float4*)(x + (size_t)m * DIM);
    i8x16 xq1[4], xq2[4], xq3[4];
#pragma unroll
    for (int kc = 0; kc < 4; ++kc) {
        float tmp[16];
#pragma unroll
        for (int j4 = 0; j4 < 4; ++j4) {
            float4 f = xr[kc * 16 + kq * 4 + j4];
            tmp[j4 * 4 + 0] = f.x; tmp[j4 * 4 + 1] = f.y;
            tmp[j4 * 4 + 2] = f.z; tmp[j4 * 4 + 3] = f.w;
        }
        i8x16 v1, v2, v3;
#pragma unroll
        for (int j = 0; j < 16; ++j) {
            char a, b, c;
            quant3(tmp[j], a, b, c);
            v1[j] = a; v2[j] = b; v3[j] = c;
        }
        xq1[kc] = v1; xq2[kc] = v2; xq3[kc] = v3;
    }

    float best = 3.4e38f;
    int bidx = 0;
    int b3 = 0;        // current stage buffer (cycles 0,1,2)
    const int* csqL = (const int*)(lds_c + 73728);

    for (int t = 0; t < 64; ++t) {
        // steady state: {stage(t), stage(t+1)} outstanding (6 loads); wait
        // own stage(t) (leave 3). t=0 also drains csq. Last tile: drain all.
        if (t == 63) {
            asm volatile("s_waitcnt vmcnt(0)" ::: "memory");
        } else {
            asm volatile("s_waitcnt vmcnt(3)" ::: "memory");
        }
        __builtin_amdgcn_s_barrier();
        __builtin_amdgcn_sched_barrier(0);
        // issue stage(t+2) into buf (b3+2)%3: fully read at tile t-1 and
        // sealed by the barrier just crossed (all waves past it).
        if (t + 2 < 64) {
            int pn = b3 + 2; if (pn >= 3) pn -= 3;
            char* d = lds_c + pn * 24576;
            const char* src = c_q + (size_t)(t + 2) * 24576;
            GLD16(src + tid * 16,        d + tid * 16);
            GLD4 (src + 16384 + tid * 4, d + 16384 + tid * 4);
            GLD4 (src + 20480 + tid * 4, d + 20480 + tid * 4);
        }
        const char* cb = lds_c + b3 * 24576;
        i32x4 accA0 = {}, accB0 = {}, accC0 = {};
        i32x4 accA1 = {}, accB1 = {}, accC1 = {};
        __builtin_amdgcn_s_setprio(1);
#pragma unroll
        for (int kc = 0; kc < 4; ++kc) {
            const int off = kc * 1024 + lane * 16;
            i32x4 c1a = __builtin_bit_cast(i32x4, *(const i8x16*)(cb + off));
            i32x4 c2a = __builtin_bit_cast(i32x4, *(const i8x16*)(cb + 8192 + off));
            i32x4 c3a = __builtin_bit_cast(i32x4, *(const i8x16*)(cb + 16384 + off));
            i32x4 c1b = __builtin_bit_cast(i32x4, *(const i8x16*)(cb + 4096 + off));
            i32x4 c2b = __builtin_bit_cast(i32x4, *(const i8x16*)(cb + 12288 + off));
            i32x4 c3b = __builtin_bit_cast(i32x4, *(const i8x16*)(cb + 20480 + off));
            i32x4 x1 = __builtin_bit_cast(i32x4, xq1[kc]);
            i32x4 x2 = __builtin_bit_cast(i32x4, xq2[kc]);
            i32x4 x3 = __builtin_bit_cast(i32x4, xq3[kc]);
            // 6 independent acc chains, g0/g1 interleaved for dep spacing
            accA0 = __builtin_amdgcn_mfma_i32_16x16x64_i8(c1a, x1, accA0, 0, 0, 0);
            accA1 = __builtin_amdgcn_mfma_i32_16x16x64_i8(c1b, x1, accA1, 0, 0, 0);
            accB0 = __builtin_amdgcn_mfma_i32_16x16x64_i8(c1a, x2, accB0, 0, 0, 0);
            accB1 = __builtin_amdgcn_mfma_i32_16x16x64_i8(c1b, x2, accB1, 0, 0, 0);
            accC0 = __builtin_amdgcn_mfma_i32_16x16x64_i8(c2a, x2, accC0, 0, 0, 0);
            accC1 = __builtin_amdgcn_mfma_i32_16x16x64_i8(c2b, x2, accC1, 0, 0, 0);
            accB0 = __builtin_amdgcn_mfma_i32_16x16x64_i8(c2a, x1, accB0, 0, 0, 0);
            accB1 = __builtin_amdgcn_mfma_i32_16x16x64_i8(c2b, x1, accB1, 0, 0, 0);
            accC0 = __builtin_amdgcn_mfma_i32_16x16x64_i8(c1a, x3, accC0, 0, 0, 0);
            accC1 = __builtin_amdgcn_mfma_i32_16x16x64_i8(c1b, x3, accC1, 0, 0, 0);
            accC0 = __builtin_amdgcn_mfma_i32_16x16x64_i8(c3a, x1, accC0, 0, 0, 0);
            accC1 = __builtin_amdgcn_mfma_i32_16x16x64_i8(c3b, x1, accC1, 0, 0, 0);
        }
        __builtin_amdgcn_s_setprio(0);
        b3 += 1; if (b3 == 3) b3 = 0;

        // epilogue: v = csq254 - (254*A + B) - C/254 (254x score, same argmin)
        // D: col = p16, row = kq*4 + r ; n = t*32 + g*16 + kq*4 + r
        {
            int4 cs0 = *(const int4*)(csqL + t * 32 + kq * 4);
            int4 cs1 = *(const int4*)(csqL + t * 32 + 16 + kq * 4);
            const int n0 = t * 32 + kq * 4;
            int csa0[4] = {cs0.x, cs0.y, cs0.z, cs0.w};
            int csa1[4] = {cs1.x, cs1.y, cs1.z, cs1.w};
#pragma unroll
            for (int r = 0; r < 4; ++r) {
                int D0 = __mul24(accA0[r], 254) + accB0[r];  // exact, |A|<2^23
                float v0 = fmaf((float)accC0[r], -R2, (float)(csa0[r] - D0));
                if (v0 < best) { best = v0; bidx = n0 + r; }
            }
#pragma unroll
            for (int r = 0; r < 4; ++r) {
                int D1 = __mul24(accA1[r], 254) + accB1[r];
                float v1 = fmaf((float)accC1[r], -R2, (float)(csa1[r] - D1));
                if (v1 < best) { best = v1; bidx = n0 + 16 + r; }
            }
        }
    }

    // merge the 4 lanes holding rows for the same point (l, l^16, l^32, l^48)
    {
        float oval = __shfl_xor(best, 16);
        int   oidx = __shfl_xor(bidx, 16);
        if (oval < best || (oval == best && oidx < bidx)) { best = oval; bidx = oidx; }
        oval = __shfl_xor(best, 32);
        oidx = __shfl_xor(bidx, 32);
        if (oval < best || (oval == best && oidx < bidx)) { best = oval; bidx = oidx; }
    }
    if (lane < 16) {
        assigns[m] = bidx;                 // m = blockIdx*256 + wv*16 + lane
        atomicAdd(&hist[bidx], 1);         // 256 atomics/block
    }
}

// Exclusive prefix sum over KC=2048 counts; one block of 256 threads x 8 each.
__global__ void scan_kernel(const int* __restrict__ hist,
                            int* __restrict__ base_,
                            int* __restrict__ cursor) {
    __shared__ int tmp[256];
    const int tid = threadIdx.x;
    int v[8], s = 0;
#pragma unroll
    for (int j = 0; j < 8; ++j) { v[j] = hist[tid * 8 + j]; s += v[j]; }
    tmp[tid] = s;
    __syncthreads();
    for (int off = 1; off < 256; off <<= 1) {
        int t = (tid >= off) ? tmp[tid - off] : 0;
        __syncthreads();
        tmp[tid] += t;
        __syncthreads();
    }
    int ex = tmp[tid] - s;
#pragma unroll
    for (int j = 0; j < 8; ++j) {
        base_[tid * 8 + j] = ex;
        cursor[tid * 8 + j] = ex;
        ex += v[j];
    }
}

__global__ void reorder_kernel(const int* __restrict__ assigns,
                               int* __restrict__ cursor,
                               int* __restrict__ order) {
    const int p = blockIdx.x * 256 + threadIdx.x;
    const int a = assigns[p];
    int pos = atomicAdd(&cursor[a], 1);
    order[pos] = p;
}

// ---------------------------------------------------------------------------
// Skew-immune segmented reduce: each block owns 256 consecutive rows of the
// SORTED order array; thread t owns dim t (coalesced 1KB row reads). Flush to
// sums[] with atomics only at cluster boundaries (block-uniform branches).
// ---------------------------------------------------------------------------
__global__ void reduce_kernel(const float* __restrict__ x,
                              const int* __restrict__ order,
                              const int* __restrict__ assigns,
                              float* __restrict__ sums) {
    const int tid = threadIdx.x;
    const int r0 = blockIdx.x * 256;
    float acc = 0.f;
    int cur = assigns[order[r0]];
    for (int r = 0; r < 256; r += 4) {
        int p0 = order[r0 + r + 0], p1 = order[r0 + r + 1];
        int p2 = order[r0 + r + 2], p3 = order[r0 + r + 3];
        float v0 = x[(size_t)p0 * DIM + tid];
        float v1 = x[(size_t)p1 * DIM + tid];
        float v2 = x[(size_t)p2 * DIM + tid];
        float v3 = x[(size_t)p3 * DIM + tid];
        int a0 = assigns[p0], a1 = assigns[p1], a2 = assigns[p2], a3 = assigns[p3];
        if (a0 != cur) { unsafeAtomicAdd(&sums[(size_t)cur * DIM + tid], acc); acc = 0.f; cur = a0; }
        acc += v0;
        if (a1 != cur) { unsafeAtomicAdd(&sums[(size_t)cur * DIM + tid], acc); acc = 0.f; cur = a1; }
        acc += v1;
        if (a2 != cur) { unsafeAtomicAdd(&sums[(size_t)cur * DIM + tid], acc); acc = 0.f; cur = a2; }
        acc += v2;
        if (a3 != cur) { unsafeAtomicAdd(&sums[(size_t)cur * DIM + tid], acc); acc = 0.f; cur = a3; }
        acc += v3;
    }
    unsafeAtomicAdd(&sums[(size_t)cur * DIM + tid], acc);
}

__global__ void finalize_kernel(const float* __restrict__ sums,
                                const int* __restrict__ hist,
                                const float* __restrict__ cen,
                                float* __restrict__ out) {
    const int id = blockIdx.x * 256 + threadIdx.x;   // KC*64 items
    const int k = id >> 6;
    const int cnt = hist[k];
    float4 s = ((const float4*)sums)[id];
    float4 c = ((const float4*)cen)[id];
    float4 o;
    if (cnt > 0) {
        float r = 1.0f / (float)cnt;
        o.x = s.x * r; o.y = s.y * r; o.z = s.z * r; o.w = s.w * r;
    } else {
        o = c;
    }
    ((float4*)out)[id] = o;
}

extern "C" void kernel_launch(void* const* d_in, const int* in_sizes, int n_in,
                              void* d_out, int out_size, void* d_ws, size_t ws_size,
                              hipStream_t stream) {
    (void)in_sizes; (void)n_in; (void)out_size; (void)ws_size;
    const float* x   = (const float*)d_in[0];
    const float* cen = (const float*)d_in[1];
    float* out = (float*)d_out;

    char* ws = (char*)d_ws;
    size_t off = 0;
    char* c_q = (char*)(ws + off);           off += (size_t)3 * KC * DIM;      // 1.5MB
    int* c_sqi = (int*)(ws + off);           off += (size_t)KC * 4;            // 8KB
    int* assigns = (int*)(ws + off);         off += (size_t)NPTS * 4;          // 512KB
    int* hist = (int*)(ws + off);            off += (size_t)KC * 4;            // 8KB
    int* base_ = (int*)(ws + off);           off += (size_t)KC * 4;            // 8KB
    int* cursor = (int*)(ws + off);          off += (size_t)KC * 4;            // 8KB
    int* order = (int*)(ws + off);           off += (size_t)NPTS * 4;          // 512KB
    float* sums = (float*)(ws + off);        off += (size_t)KC * DIM * 4;      // 2MB

    cprep_kernel<<<KC / 4, 256, 0, stream>>>(cen, c_q, c_sqi, hist, sums);
    assign_kernel<<<NPTS / 256, 1024, 0, stream>>>(x, c_q, c_sqi, assigns, hist);
    scan_kernel<<<1, 256, 0, stream>>>(hist, base_, cursor);
    reorder_kernel<<<NPTS / 256, 256, 0, stream>>>(assigns, cursor, order);
    reduce_kernel<<<NPTS / 256, 256, 0, stream>>>(x, order, assigns, sums);
    finalize_kernel<<<KC * 64 / 256, 256, 0, stream>>>(sums, hist, cen, out);
}

// Round 13
// 566.233 us; speedup vs baseline: 5.0667x; 1.0657x over previous
//
#include <hip/hip_runtime.h>

typedef unsigned short u16;
typedef unsigned int u32;
typedef unsigned long long u64;
typedef __attribute__((ext_vector_type(4)))  int  i32x4;
typedef __attribute__((ext_vector_type(16))) char i8x16;

#define NPTS 131072
#define DIM  256
#define KC   2048

// 3-level fixed point: v = S1*q1 + S2*q2 + S3*q3 + eps, |eps| <= S3/2 ~ 4.8e-7
// Ratio 254 => rint(r*INV) in [-127,127]: no clamp cascade (q2/q3 clamps are
// mathematically redundant when q1 is in range: |r1| <= S1/2 -> |q2| <= 127).
// Identity S1*S3 == S2*S2 lets q2q2, q1q3, q3q1 share one accumulator weight.
constexpr float S1  = 0.0625f;                 // 127*S1 = 7.94 > max|N(0,1)|
constexpr float S2  = S1 / 254.0f;
constexpr float S3  = S2 * S2 / S1;            // = S2/254
constexpr float IS1 = 16.0f;
constexpr float IS2 = 4064.0f;                 // 254/S1
constexpr float IS3 = 1.0f / S3;
constexpr float W_A = S1 * S1;
// epilogue compares 254-scaled: v = csq254 - (254*A + B) - C/254
constexpr float R2  = 1.0f / 254.0f;

__device__ inline void quant3(float v, char& q1, char& q2, char& q3) {
    float a = fminf(fmaxf(rintf(v * IS1), -127.f), 127.f);
    float r1 = fmaf(-a, S1, v);                // exact (pow2 scale)
    float b = rintf(r1 * IS2);                 // |r1|<=S1/2 -> |b|<=127, no clamp
    float r2 = fmaf(-b, S2, r1);               // ~1-ulp error, absorbed by q3
    float c = rintf(r2 * IS3);                 // |r2|<=S2/2 -> |c|<=127
    q1 = (char)a; q2 = (char)b; q3 = (char)c;
}

// global -> LDS direct DMA, 16B per lane (wave-uniform base + lane*16)
#define GLD16(gsrc, ldst) \
    __builtin_amdgcn_global_load_lds( \
        (const __attribute__((address_space(1))) void*)(gsrc), \
        (__attribute__((address_space(3))) void*)(ldst), 16, 0, 0)

// ---------------------------------------------------------------------------
// Centroid prep for 16x16x64 i8 MFMA A-fragments + int 254-scaled 0.5||c||^2.
// (Round-8 verified layout.) Plane layout (per level): for centroid n
// (g16=n>>4, c=n&15), dim d (kc=d>>6, kq=(d>>4)&3, j=d&15):
//   byte = ((g16*4+kc)*64 + kq*16 + c)*16 + j.
// Level l at plane offset l*KC*DIM. Also zeroes hist (blocks 0..7) and sums.
// ---------------------------------------------------------------------------
__global__ void cprep_kernel(const float* __restrict__ cen,
                             char* __restrict__ c_q,
                             int* __restrict__ c_sqi,
                             int* __restrict__ hist,
                             float* __restrict__ sums) {
    if (blockIdx.x < 8) hist[blockIdx.x * 256 + threadIdx.x] = 0;
    ((float4*)sums)[blockIdx.x * 256 + threadIdx.x] = (float4){0.f, 0.f, 0.f, 0.f};
    const int lane = threadIdx.x & 63;
    const int wv   = threadIdx.x >> 6;
    const int n    = blockIdx.x * 4 + wv;               // centroid row
    float4 v = ((const float4*)(cen + (size_t)n * DIM))[lane];  // dims lane*4..+3
    float ss = v.x * v.x + v.y * v.y + v.z * v.z + v.w * v.w;
    float fv[4] = {v.x, v.y, v.z, v.w};
    char q1[4], q2[4], q3[4];
#pragma unroll
    for (int j = 0; j < 4; ++j) quant3(fv[j], q1[j], q2[j], q3[j]);
    const int g16 = n >> 4, c = n & 15;
    const int kc  = lane >> 4;
    const int kq  = (lane >> 2) & 3;
    const size_t base = ((size_t)((g16 * 4 + kc) * 64 + kq * 16 + c)) * 16
                        + (lane & 3) * 4;
    u32 p1 = (u32)(unsigned char)q1[0] | ((u32)(unsigned char)q1[1] << 8) |
             ((u32)(unsigned char)q1[2] << 16) | ((u32)(unsigned char)q1[3] << 24);
    u32 p2 = (u32)(unsigned char)q2[0] | ((u32)(unsigned char)q2[1] << 8) |
             ((u32)(unsigned char)q2[2] << 16) | ((u32)(unsigned char)q2[3] << 24);
    u32 p3 = (u32)(unsigned char)q3[0] | ((u32)(unsigned char)q3[1] << 8) |
             ((u32)(unsigned char)q3[2] << 16) | ((u32)(unsigned char)q3[3] << 24);
    *(u32*)(c_q + base) = p1;
    *(u32*)(c_q + (size_t)KC * DIM + base) = p2;
    *(u32*)(c_q + (size_t)2 * KC * DIM + base) = p3;
#pragma unroll
    for (int off = 32; off > 0; off >>= 1) ss += __shfl_xor(ss, off);
    if (lane == 0) c_sqi[n] = (int)rintf(ss * (0.5f * 254.0f / W_A));
}

// ---------------------------------------------------------------------------
// Assignment via mfma_i32_16x16x64_i8 — ROUND-8 VERIFIED BEST (342 us,
// VGPR 64, 16 waves/CU, MfmaUtil 58.5, zero spill). Wave owns 16 points x
// all 2048 centroids; 512-thr blocks (8 waves), 2 blocks/CU (80KB LDS each);
// 3-deep full-tile ring, counted vmcnt(3) (never 0 mid-loop); csq in LDS
// keeps the loop free of non-staging vmem.
// Session map (R0-R12): residency plateau is 16 waves/CU — 32-wave paths are
// LDS-blocked (R12: 2x80KB doesn't co-schedule), denser-wave paths spill at
// the 128-reg cliff (R4/R9/R11). At this point LDS-read ~72% and MFMA ~61%
// of the tile wall are both live; schedule variants all land within +-10%.
// Per cen-group g: accA += q1c*q1x; accB += q1c*q2x + q2c*q1x;
// accC += q2c*q2x + q1c*q3x + q3c*q1x.
// Epilogue: v = csq254 - (254*A + B) - C/254   (mul24 exact, |A| < 2^23)
// D layout: col = lane&15 (point), row = (lane>>4)*4 + reg (m89/m121).
// ---------------------------------------------------------------------------
__global__ __launch_bounds__(512, 4) void assign_kernel(
    const float* __restrict__ x, const char* __restrict__ c_q,
    const int* __restrict__ c_sqi, int* __restrict__ assigns,
    int* __restrict__ hist) {
    __shared__ char lds_c[3 * 24576 + 8192];   // 3 stage bufs + csq = 80KB

    const int tid  = threadIdx.x;       // 0..511
    const int lane = tid & 63;
    const int wv   = tid >> 6;          // 0..7
    const int p16  = lane & 15;         // point within wave's 16
    const int kq   = lane >> 4;         // K-quarter / D-row group

    const char* cl1 = c_q;
    const char* cl2 = c_q + (size_t)KC * DIM;
    const char* cl3 = c_q + (size_t)2 * KC * DIM;

    // ---- prologue DMA (latency hidden under quantization VALU) ----
    GLD16((const char*)c_sqi + tid * 16, lds_c + 73728 + tid * 16);   // 8KB csq
    GLD16(cl1 + tid * 16,        lds_c + tid * 16);                   // stage 0
    GLD16(cl2 + tid * 16,        lds_c + 8192 + tid * 16);
    GLD16(cl3 + tid * 16,        lds_c + 16384 + tid * 16);
    GLD16(cl1 + 8192 + tid * 16, lds_c + 24576 + tid * 16);           // stage 1
    GLD16(cl2 + 8192 + tid * 16, lds_c + 24576 + 8192 + tid * 16);
    GLD16(cl3 + 8192 + tid * 16, lds_c + 24576 + 16384 + tid * 16);

    // ---- quantize: lane holds point m, dims kc*64 + kq*16 + (0..15) ----
    const int m = blockIdx.x * 128 + wv * 16 + p16;
    const float4* xr = (const float4*)(x + (size_t)m * DIM);
    i8x16 xq1[4], xq2[4], xq3[4];
#pragma unroll
    for (int kc = 0; kc < 4; ++kc) {
        float tmp[16];
#pragma unroll
        for (int j4 = 0; j4 < 4; ++j4) {
            float4 f = xr[kc * 16 + kq * 4 + j4];
            tmp[j4 * 4 + 0] = f.x; tmp[j4 * 4 + 1] = f.y;
            tmp[j4 * 4 + 2] = f.z; tmp[j4 * 4 + 3] = f.w;
        }
        i8x16 v1, v2, v3;
#pragma unroll
        for (int j = 0; j < 16; ++j) {
            char a, b, c;
            quant3(tmp[j], a, b, c);
            v1[j] = a; v2[j] = b; v3[j] = c;
        }
        xq1[kc] = v1; xq2[kc] = v2; xq3[kc] = v3;
    }

    float best = 3.4e38f;
    int bidx = 0;
    int b3 = 0;        // current stage buffer (cycles 0,1,2)
    const int* csqL = (const int*)(lds_c + 73728);

    for (int t = 0; t < 64; ++t) {
        if (t == 63) {
            asm volatile("s_waitcnt vmcnt(0)" ::: "memory");
        } else {
            asm volatile("s_waitcnt vmcnt(3)" ::: "memory");
        }
        __builtin_amdgcn_s_barrier();
        __builtin_amdgcn_sched_barrier(0);
        // issue stage(t+2) into buf (b3+2)%3: fully read at tile t-1 and
        // sealed by the barrier just crossed (all waves past it).
        if (t + 2 < 64) {
            int pn = b3 + 2; if (pn >= 3) pn -= 3;
            char* d = lds_c + pn * 24576;
            const size_t so = (size_t)(t + 2) * 8192;
            GLD16(cl1 + so + tid * 16, d + tid * 16);
            GLD16(cl2 + so + tid * 16, d + 8192 + tid * 16);
            GLD16(cl3 + so + tid * 16, d + 16384 + tid * 16);
        }
        const char* cb = lds_c + b3 * 24576;
        i32x4 accA0 = {}, accB0 = {}, accC0 = {};
        i32x4 accA1 = {}, accB1 = {}, accC1 = {};
        __builtin_amdgcn_s_setprio(1);
#pragma unroll
        for (int kc = 0; kc < 4; ++kc) {
            const int off = kc * 1024 + lane * 16;
            i32x4 c1a = __builtin_bit_cast(i32x4, *(const i8x16*)(cb + off));
            i32x4 c2a = __builtin_bit_cast(i32x4, *(const i8x16*)(cb + 8192 + off));
            i32x4 c3a = __builtin_bit_cast(i32x4, *(const i8x16*)(cb + 16384 + off));
            i32x4 c1b = __builtin_bit_cast(i32x4, *(const i8x16*)(cb + 4096 + off));
            i32x4 c2b = __builtin_bit_cast(i32x4, *(const i8x16*)(cb + 12288 + off));
            i32x4 c3b = __builtin_bit_cast(i32x4, *(const i8x16*)(cb + 20480 + off));
            i32x4 x1 = __builtin_bit_cast(i32x4, xq1[kc]);
            i32x4 x2 = __builtin_bit_cast(i32x4, xq2[kc]);
            i32x4 x3 = __builtin_bit_cast(i32x4, xq3[kc]);
            // 6 independent acc chains, g0/g1 interleaved for dep spacing
            accA0 = __builtin_amdgcn_mfma_i32_16x16x64_i8(c1a, x1, accA0, 0, 0, 0);
            accA1 = __builtin_amdgcn_mfma_i32_16x16x64_i8(c1b, x1, accA1, 0, 0, 0);
            accB0 = __builtin_amdgcn_mfma_i32_16x16x64_i8(c1a, x2, accB0, 0, 0, 0);
            accB1 = __builtin_amdgcn_mfma_i32_16x16x64_i8(c1b, x2, accB1, 0, 0, 0);
            accC0 = __builtin_amdgcn_mfma_i32_16x16x64_i8(c2a, x2, accC0, 0, 0, 0);
            accC1 = __builtin_amdgcn_mfma_i32_16x16x64_i8(c2b, x2, accC1, 0, 0, 0);
            accB0 = __builtin_amdgcn_mfma_i32_16x16x64_i8(c2a, x1, accB0, 0, 0, 0);
            accB1 = __builtin_amdgcn_mfma_i32_16x16x64_i8(c2b, x1, accB1, 0, 0, 0);
            accC0 = __builtin_amdgcn_mfma_i32_16x16x64_i8(c1a, x3, accC0, 0, 0, 0);
            accC1 = __builtin_amdgcn_mfma_i32_16x16x64_i8(c1b, x3, accC1, 0, 0, 0);
            accC0 = __builtin_amdgcn_mfma_i32_16x16x64_i8(c3a, x1, accC0, 0, 0, 0);
            accC1 = __builtin_amdgcn_mfma_i32_16x16x64_i8(c3b, x1, accC1, 0, 0, 0);
        }
        __builtin_amdgcn_s_setprio(0);
        b3 += 1; if (b3 == 3) b3 = 0;

        // epilogue: v = csq254 - (254*A + B) - C/254 (254x score, same argmin)
        // D: col = p16, row = kq*4 + r ; n = t*32 + g*16 + kq*4 + r
        {
            int4 cs0 = *(const int4*)(csqL + t * 32 + kq * 4);
            int4 cs1 = *(const int4*)(csqL + t * 32 + 16 + kq * 4);
            const int n0 = t * 32 + kq * 4;
            int csa0[4] = {cs0.x, cs0.y, cs0.z, cs0.w};
            int csa1[4] = {cs1.x, cs1.y, cs1.z, cs1.w};
#pragma unroll
            for (int r = 0; r < 4; ++r) {
                int D0 = __mul24(accA0[r], 254) + accB0[r];  // exact, |A|<2^23
                float v0 = fmaf((float)accC0[r], -R2, (float)(csa0[r] - D0));
                if (v0 < best) { best = v0; bidx = n0 + r; }
            }
#pragma unroll
            for (int r = 0; r < 4; ++r) {
                int D1 = __mul24(accA1[r], 254) + accB1[r];
                float v1 = fmaf((float)accC1[r], -R2, (float)(csa1[r] - D1));
                if (v1 < best) { best = v1; bidx = n0 + 16 + r; }
            }
        }
    }

    // merge the 4 lanes holding rows for the same point (l, l^16, l^32, l^48)
    {
        float oval = __shfl_xor(best, 16);
        int   oidx = __shfl_xor(bidx, 16);
        if (oval < best || (oval == best && oidx < bidx)) { best = oval; bidx = oidx; }
        oval = __shfl_xor(best, 32);
        oidx = __shfl_xor(bidx, 32);
        if (oval < best || (oval == best && oidx < bidx)) { best = oval; bidx = oidx; }
    }
    if (lane < 16) {
        assigns[m] = bidx;                 // m = blockIdx*128 + wv*16 + lane
        atomicAdd(&hist[bidx], 1);         // 128 atomics/block
    }
}

// Exclusive prefix sum over KC=2048 counts; one block of 256 threads x 8 each.
__global__ void scan_kernel(const int* __restrict__ hist,
                            int* __restrict__ base_,
                            int* __restrict__ cursor) {
    __shared__ int tmp[256];
    const int tid = threadIdx.x;
    int v[8], s = 0;
#pragma unroll
    for (int j = 0; j < 8; ++j) { v[j] = hist[tid * 8 + j]; s += v[j]; }
    tmp[tid] = s;
    __syncthreads();
    for (int off = 1; off < 256; off <<= 1) {
        int t = (tid >= off) ? tmp[tid - off] : 0;
        __syncthreads();
        tmp[tid] += t;
        __syncthreads();
    }
    int ex = tmp[tid] - s;
#pragma unroll
    for (int j = 0; j < 8; ++j) {
        base_[tid * 8 + j] = ex;
        cursor[tid * 8 + j] = ex;
        ex += v[j];
    }
}

__global__ void reorder_kernel(const int* __restrict__ assigns,
                               int* __restrict__ cursor,
                               int* __restrict__ order) {
    const int p = blockIdx.x * 256 + threadIdx.x;
    const int a = assigns[p];
    int pos = atomicAdd(&cursor[a], 1);
    order[pos] = p;
}

// ---------------------------------------------------------------------------
// Skew-immune segmented reduce: each block owns 256 consecutive rows of the
// SORTED order array; thread t owns dim t (coalesced 1KB row reads). Flush to
// sums[] with atomics only at cluster boundaries (block-uniform branches).
// ---------------------------------------------------------------------------
__global__ void reduce_kernel(const float* __restrict__ x,
                              const int* __restrict__ order,
                              const int* __restrict__ assigns,
                              float* __restrict__ sums) {
    const int tid = threadIdx.x;
    const int r0 = blockIdx.x * 256;
    float acc = 0.f;
    int cur = assigns[order[r0]];
    for (int r = 0; r < 256; r += 4) {
        int p0 = order[r0 + r + 0], p1 = order[r0 + r + 1];
        int p2 = order[r0 + r + 2], p3 = order[r0 + r + 3];
        float v0 = x[(size_t)p0 * DIM + tid];
        float v1 = x[(size_t)p1 * DIM + tid];
        float v2 = x[(size_t)p2 * DIM + tid];
        float v3 = x[(size_t)p3 * DIM + tid];
        int a0 = assigns[p0], a1 = assigns[p1], a2 = assigns[p2], a3 = assigns[p3];
        if (a0 != cur) { unsafeAtomicAdd(&sums[(size_t)cur * DIM + tid], acc); acc = 0.f; cur = a0; }
        acc += v0;
        if (a1 != cur) { unsafeAtomicAdd(&sums[(size_t)cur * DIM + tid], acc); acc = 0.f; cur = a1; }
        acc += v1;
        if (a2 != cur) { unsafeAtomicAdd(&sums[(size_t)cur * DIM + tid], acc); acc = 0.f; cur = a2; }
        acc += v2;
        if (a3 != cur) { unsafeAtomicAdd(&sums[(size_t)cur * DIM + tid], acc); acc = 0.f; cur = a3; }
        acc += v3;
    }
    unsafeAtomicAdd(&sums[(size_t)cur * DIM + tid], acc);
}

__global__ void finalize_kernel(const float* __restrict__ sums,
                                const int* __restrict__ hist,
                                const float* __restrict__ cen,
                                float* __restrict__ out) {
    const int id = blockIdx.x * 256 + threadIdx.x;   // KC*64 items
    const int k = id >> 6;
    const int cnt = hist[k];
    float4 s = ((const float4*)sums)[id];
    float4 c = ((const float4*)cen)[id];
    float4 o;
    if (cnt > 0) {
        float r = 1.0f / (float)cnt;
        o.x = s.x * r; o.y = s.y * r; o.z = s.z * r; o.w = s.w * r;
    } else {
        o = c;
    }
    ((float4*)out)[id] = o;
}

extern "C" void kernel_launch(void* const* d_in, const int* in_sizes, int n_in,
                              void* d_out, int out_size, void* d_ws, size_t ws_size,
                              hipStream_t stream) {
    (void)in_sizes; (void)n_in; (void)out_size; (void)ws_size;
    const float* x   = (const float*)d_in[0];
    const float* cen = (const float*)d_in[1];
    float* out = (float*)d_out;

    char* ws = (char*)d_ws;
    size_t off = 0;
    char* c_q = (char*)(ws + off);           off += (size_t)3 * KC * DIM;      // 1.5MB
    int* c_sqi = (int*)(ws + off);           off += (size_t)KC * 4;            // 8KB
    int* assigns = (int*)(ws + off);         off += (size_t)NPTS * 4;          // 512KB
    int* hist = (int*)(ws + off);            off += (size_t)KC * 4;            // 8KB
    int* base_ = (int*)(ws + off);           off += (size_t)KC * 4;            // 8KB
    int* cursor = (int*)(ws + off);          off += (size_t)KC * 4;            // 8KB
    int* order = (int*)(ws + off);           off += (size_t)NPTS * 4;          // 512KB
    float* sums = (float*)(ws + off);        off += (size_t)KC * DIM * 4;      // 2MB

    cprep_kernel<<<KC / 4, 256, 0, stream>>>(cen, c_q, c_sqi, hist, sums);
    assign_kernel<<<NPTS / 128, 512, 0, stream>>>(x, c_q, c_sqi, assigns, hist);
    scan_kernel<<<1, 256, 0, stream>>>(hist, base_, cursor);
    reorder_kernel<<<NPTS / 256, 256, 0, stream>>>(assigns, cursor, order);
    reduce_kernel<<<NPTS / 256, 256, 0, stream>>>(x, order, assigns, sums);
    finalize_kernel<<<KC * 64 / 256, 256, 0, stream>>>(sums, hist, cen, out);
}